// Round 4
// baseline (288.186 us; speedup 1.0000x reference)
//
#include <hip/hip_runtime.h>
#include <math.h>

#define C 512
#define HW 4096
#define N 1024
#define NPIX 32768
#define MARGIN 2.0f
#define CAP 512

typedef short s16x8 __attribute__((ext_vector_type(8)));
typedef float f32x4 __attribute__((ext_vector_type(4)));

__device__ inline unsigned short f2bf(float f) {
    unsigned int u = __float_as_uint(f);
    return (unsigned short)((u + 0x7FFFu + ((u >> 16) & 1u)) >> 16);
}
__device__ inline float h2f(unsigned short u) {
    _Float16 h; __builtin_memcpy(&h, &u, 2); return (float)h;
}
__device__ inline unsigned short f2h(float f) {
    _Float16 h = (_Float16)f; unsigned short u; __builtin_memcpy(&u, &h, 2); return u;
}
__device__ inline unsigned int mono(float v) {
    unsigned int u = __float_as_uint(v);
    return (u & 0x80000000u) ? ~u : (u | 0x80000000u);
}
__device__ inline float unmono(unsigned int u) {
    unsigned int v = (u & 0x80000000u) ? (u & 0x7FFFFFFFu) : ~u;
    return __uint_as_float(v);
}
// xs layout: [px][k], 16B-granule XOR swizzle: granule G of pixel px stored at G^(px&7)
__device__ inline int xsw(int px, int G) { return px * 512 + ((G ^ (px & 7)) << 2); }

// ---------- K0: row norms of centers (->cnorm) and clusters (->clnorm) ----------
__global__ __launch_bounds__(64) void k_norms(const float* __restrict__ centers,
                                              const float* __restrict__ clusters,
                                              float* __restrict__ cnorm,
                                              float* __restrict__ clnorm) {
    int r = blockIdx.x;
    const float* src = (r < N) ? (centers + (size_t)r * C) : (clusters + (size_t)(r - N) * C);
    int lane = threadIdx.x;
    float s = 0.f;
    for (int k = lane; k < C; k += 64) { float v = src[k]; s += v * v; }
    #pragma unroll
    for (int m = 1; m < 64; m <<= 1) s += __shfl_xor(s, m, 64);
    if (lane == 0) {
        float nrm = sqrtf(s);
        if (nrm < 1e-12f) nrm = 1e-12f;
        if (r < N) cnorm[r] = nrm; else clnorm[r - N] = nrm;
    }
}

// ---------- K1: M[i][j] = dot(centers[i],clusters[j]) / (cnorm[i]*clnorm[j]) ----------
__global__ __launch_bounds__(256) void k_gemmM(const float* __restrict__ centers,
                                               const float* __restrict__ clusters,
                                               const float* __restrict__ cnorm,
                                               const float* __restrict__ clnorm,
                                               float* __restrict__ M) {
    __shared__ float as[32][68];
    __shared__ float bs[32][68];
    int tid = threadIdx.x;
    int tx = tid & 15, ty = tid >> 4;
    int i0 = blockIdx.x * 64, j0 = blockIdx.y * 64;
    int lrow = tid >> 2, lkq = (tid & 3) * 8;
    float acc[4][4] = {};
    for (int kc = 0; kc < C; kc += 32) {
        float4 a0 = *(const float4*)(centers + (size_t)(i0 + lrow) * C + kc + lkq);
        float4 a1 = *(const float4*)(centers + (size_t)(i0 + lrow) * C + kc + lkq + 4);
        float4 b0 = *(const float4*)(clusters + (size_t)(j0 + lrow) * C + kc + lkq);
        float4 b1 = *(const float4*)(clusters + (size_t)(j0 + lrow) * C + kc + lkq + 4);
        __syncthreads();
        as[lkq+0][lrow]=a0.x; as[lkq+1][lrow]=a0.y; as[lkq+2][lrow]=a0.z; as[lkq+3][lrow]=a0.w;
        as[lkq+4][lrow]=a1.x; as[lkq+5][lrow]=a1.y; as[lkq+6][lrow]=a1.z; as[lkq+7][lrow]=a1.w;
        bs[lkq+0][lrow]=b0.x; bs[lkq+1][lrow]=b0.y; bs[lkq+2][lrow]=b0.z; bs[lkq+3][lrow]=b0.w;
        bs[lkq+4][lrow]=b1.x; bs[lkq+5][lrow]=b1.y; bs[lkq+6][lrow]=b1.z; bs[lkq+7][lrow]=b1.w;
        __syncthreads();
        #pragma unroll
        for (int k = 0; k < 32; k += 4) {
            float av[4][4], bv[4][4];
            #pragma unroll
            for (int kk = 0; kk < 4; ++kk) {
                float4 ta = *(const float4*)&as[k+kk][tx*4];
                float4 tb = *(const float4*)&bs[k+kk][ty*4];
                av[kk][0]=ta.x; av[kk][1]=ta.y; av[kk][2]=ta.z; av[kk][3]=ta.w;
                bv[kk][0]=tb.x; bv[kk][1]=tb.y; bv[kk][2]=tb.z; bv[kk][3]=tb.w;
            }
            #pragma unroll
            for (int kk = 0; kk < 4; ++kk)
                #pragma unroll
                for (int ii = 0; ii < 4; ++ii)
                    #pragma unroll
                    for (int jj = 0; jj < 4; ++jj)
                        acc[ii][jj] = fmaf(av[kk][ii], bv[kk][jj], acc[ii][jj]);
        }
    }
    float rci[4], rcj[4];
    #pragma unroll
    for (int ii = 0; ii < 4; ++ii) rci[ii] = cnorm[i0 + tx*4 + ii];
    #pragma unroll
    for (int jj = 0; jj < 4; ++jj) rcj[jj] = clnorm[j0 + ty*4 + jj];
    #pragma unroll
    for (int ii = 0; ii < 4; ++ii)
        #pragma unroll
        for (int jj = 0; jj < 4; ++jj)
            M[(size_t)(i0 + tx*4 + ii) * N + (j0 + ty*4 + jj)] = acc[ii][jj] / (rci[ii] * rcj[jj]);
}

// ---------- K2: per-row max + argmax (first-index tie-break) of M ----------
__global__ __launch_bounds__(256) void k_rowstat(const float* __restrict__ M,
                                                 float* __restrict__ rowmax,
                                                 int* __restrict__ rowarg) {
    __shared__ float sv[256];
    __shared__ int   sa[256];
    int i = blockIdx.x, tid = threadIdx.x;
    float bv = -INFINITY; int ba = 0;
    for (int j = tid; j < N; j += 256) {
        float v = M[(size_t)i * N + j];
        if (v > bv || (v == bv && j < ba)) { bv = v; ba = j; }
    }
    sv[tid] = bv; sa[tid] = ba;
    __syncthreads();
    for (int s = 128; s > 0; s >>= 1) {
        if (tid < s) {
            float v = sv[tid + s]; int a = sa[tid + s];
            if (v > sv[tid] || (v == sv[tid] && a < sa[tid])) { sv[tid] = v; sa[tid] = a; }
        }
        __syncthreads();
    }
    if (tid == 0) { rowmax[i] = sv[0]; rowarg[i] = sa[0]; }
}

// ---------- K3: centers -> bf16 MFMA B-fragments (fragment-linear) ----------
__global__ __launch_bounds__(64) void k_cenfrag(const float* __restrict__ centers,
                                                unsigned short* __restrict__ cenB) {
    int f = blockIdx.x;                 // nt*16 + kt
    int nt = f >> 4, kt = f & 15;
    int lane = threadIdx.x;
    int r = lane & 15, g = lane >> 4;
    const float* src = centers + (size_t)(nt * 16 + r) * C + kt * 32 + g * 4;
    float4 lo = *(const float4*)src;
    float4 hi = *(const float4*)(src + 16);
    union { unsigned short us[8]; uint4 q; } u;
    u.us[0]=f2bf(lo.x); u.us[1]=f2bf(lo.y); u.us[2]=f2bf(lo.z); u.us[3]=f2bf(lo.w);
    u.us[4]=f2bf(hi.x); u.us[5]=f2bf(hi.y); u.us[6]=f2bf(hi.z); u.us[7]=f2bf(hi.w);
    *(uint4*)(cenB + ((size_t)f * 64 + lane) * 8) = u.q;
}

// ---------- K4: FUSED — MFMA logits (fp16 in regs) -> max -> candidates -> exact refine -> idx ----------
__global__ __launch_bounds__(256, 3) void k_fused(const float* __restrict__ x,
                                                  const unsigned short* __restrict__ cenB,
                                                  const float* __restrict__ gumbel,
                                                  const float* __restrict__ centers,
                                                  int* __restrict__ idxb) {
    __shared__ float xs[C * 16];                 // [px][k] fp32, XOR-swizzled 16B granules, 32 KB
    __shared__ unsigned int pmax[16];
    __shared__ unsigned long long pixkey[16];
    __shared__ unsigned int candlist[CAP];
    __shared__ int candcount;

    int tid = threadIdx.x;
    int lane = tid & 63, w = tid >> 6;
    int r = lane & 15, g = lane >> 4;

    // block -> pixel tile, swizzled so consecutive tiles share an XCD
    int tile = (int)((blockIdx.x >> 3) | ((blockIdx.x & 7) << 8));
    int p0 = tile << 4;
    int b = p0 >> 12, hw0 = p0 & (HW - 1);

    if (tid < 16) { pmax[tid] = 0u; pixkey[tid] = 0ull; }
    if (tid == 0) candcount = 0;

    // ---- stage x tile: read [k][4px] float4 coalesced, write scalars swizzled ----
    const float* xb = x + (size_t)b * C * HW + hw0;
    {
        int k0 = tid >> 2, q = (tid & 3) << 2;
        #pragma unroll
        for (int kk = 0; kk < 8; ++kk) {
            int k = kk * 64 + k0;
            float4 v = *(const float4*)(xb + (size_t)k * HW + q);
            int G = k >> 2, e = k & 3;
            xs[xsw(q + 0, G) + e] = v.x;
            xs[xsw(q + 1, G) + e] = v.y;
            xs[xsw(q + 2, G) + e] = v.z;
            xs[xsw(q + 3, G) + e] = v.w;
        }
    }
    __syncthreads();

    // ---- build A fragments (16 px x 512 k bf16) via vector LDS reads ----
    s16x8 a[16];
    #pragma unroll
    for (int kt = 0; kt < 16; ++kt) {
        float4 lo = *(const float4*)&xs[xsw(r, kt * 8 + g)];
        float4 hi = *(const float4*)&xs[xsw(r, kt * 8 + g + 4)];
        s16x8 t;
        t[0] = (short)f2bf(lo.x); t[1] = (short)f2bf(lo.y);
        t[2] = (short)f2bf(lo.z); t[3] = (short)f2bf(lo.w);
        t[4] = (short)f2bf(hi.x); t[5] = (short)f2bf(hi.y);
        t[6] = (short)f2bf(hi.z); t[7] = (short)f2bf(hi.w);
        a[kt] = t;
    }

    // ---- MFMA over this wave's 256 n; logits packed fp16 in regs; running fp32 max ----
    unsigned int keepH[32];
    float m4[4] = {-INFINITY, -INFINITY, -INFINITY, -INFINITY};
    const float* grow = gumbel + ((size_t)b * N + r) * HW + hw0 + g * 4;
    #pragma unroll
    for (int nt = 0; nt < 16; ++nt) {
        int ntg = (w << 4) + nt;
        const unsigned short* bp = cenB + (size_t)ntg * 16 * 512 + lane * 8;
        float4 gv = *(const float4*)(grow + (size_t)ntg * 16 * HW);
        f32x4 acc0 = {0.f, 0.f, 0.f, 0.f};
        f32x4 acc1 = {0.f, 0.f, 0.f, 0.f};
        #pragma unroll
        for (int kt = 0; kt < 16; kt += 2) {
            s16x8 b0 = *(const s16x8*)(bp + (size_t)kt * 512);
            s16x8 b1 = *(const s16x8*)(bp + (size_t)(kt + 1) * 512);
            acc0 = __builtin_amdgcn_mfma_f32_16x16x32_bf16(a[kt],     b0, acc0, 0, 0, 0);
            acc1 = __builtin_amdgcn_mfma_f32_16x16x32_bf16(a[kt + 1], b1, acc1, 0, 0, 0);
        }
        float v0 = acc0[0] + acc1[0] + gv.x;
        float v1 = acc0[1] + acc1[1] + gv.y;
        float v2 = acc0[2] + acc1[2] + gv.z;
        float v3 = acc0[3] + acc1[3] + gv.w;
        m4[0] = fmaxf(m4[0], v0); m4[1] = fmaxf(m4[1], v1);
        m4[2] = fmaxf(m4[2], v2); m4[3] = fmaxf(m4[3], v3);
        keepH[nt * 2]     = (unsigned int)f2h(v0) | ((unsigned int)f2h(v1) << 16);
        keepH[nt * 2 + 1] = (unsigned int)f2h(v2) | ((unsigned int)f2h(v3) << 16);
    }

    // ---- per-pixel approx max: shfl over r (n within tile), LDS atomic over waves ----
    #pragma unroll
    for (int s2 = 1; s2 < 16; s2 <<= 1)
        #pragma unroll
        for (int j = 0; j < 4; ++j) m4[j] = fmaxf(m4[j], __shfl_xor(m4[j], s2, 64));
    if (r == 0) {
        #pragma unroll
        for (int j = 0; j < 4; ++j) atomicMax(&pmax[g * 4 + j], mono(m4[j]));
    }
    __syncthreads();

    // ---- candidate scan (margin covers bf16 MFMA + fp16 store error) ----
    float thr[4];
    #pragma unroll
    for (int j = 0; j < 4; ++j) thr[j] = unmono(pmax[g * 4 + j]) - MARGIN;
    #pragma unroll
    for (int nt = 0; nt < 16; ++nt) {
        int n0 = (((w << 4) + nt) << 4) + r;
        #pragma unroll
        for (int j2 = 0; j2 < 2; ++j2) {
            unsigned int pk = keepH[nt * 2 + j2];
            float lo = h2f((unsigned short)(pk & 0xFFFFu));
            float hi = h2f((unsigned short)(pk >> 16));
            int j = j2 * 2;
            if (lo >= thr[j]) {
                int pos = atomicAdd(&candcount, 1);
                if (pos < CAP) candlist[pos] = (unsigned int)n0 | ((unsigned int)(g * 4 + j) << 12);
            }
            if (hi >= thr[j + 1]) {
                int pos = atomicAdd(&candcount, 1);
                if (pos < CAP) candlist[pos] = (unsigned int)n0 | ((unsigned int)(g * 4 + j + 1) << 12);
            }
        }
    }
    __syncthreads();

    // ---- exact fp32 refine: 4 candidates per wave in parallel (16-lane groups) ----
    int cc = candcount; if (cc > CAP) cc = CAP;
    int sl = lane & 15, cg = lane >> 4;
    for (int t0 = w * 4; t0 < cc; t0 += 16) {
        int c = t0 + cg;
        bool valid = c < cc;
        unsigned int e = candlist[valid ? c : 0];
        int n = (int)(e & 1023u), pl = (int)(e >> 12);
        const float* cen = centers + (size_t)n * C;
        float s = 0.f;
        #pragma unroll
        for (int m = 0; m < 8; ++m) {
            int G = sl + (m << 4);
            float4 xv = *(const float4*)&xs[xsw(pl, G)];
            float4 cv = *(const float4*)(cen + (G << 2));
            s = fmaf(xv.x, cv.x, s); s = fmaf(xv.y, cv.y, s);
            s = fmaf(xv.z, cv.z, s); s = fmaf(xv.w, cv.w, s);
        }
        #pragma unroll
        for (int s2 = 1; s2 < 16; s2 <<= 1) s += __shfl_xor(s, s2, 64);
        if (valid && sl == 0) {
            float val = s + gumbel[((size_t)b * N + n) * HW + hw0 + pl];
            unsigned long long key = ((unsigned long long)mono(val) << 32) | (unsigned int)(1023 - n);
            atomicMax(&pixkey[pl], key);
        }
    }
    __syncthreads();
    if (tid < 16) idxb[p0 + tid] = 1023 - (int)(unsigned int)(pixkey[tid] & 0xFFFFFFFFull);
}

// ---------- K5: preds (as float) + per-block loss partial sums ----------
__global__ __launch_bounds__(256) void k_preds(const int* __restrict__ idxb,
                                               const float* __restrict__ rowmax,
                                               const int* __restrict__ rowarg,
                                               float* __restrict__ preds_out,
                                               float* __restrict__ partial) {
    __shared__ float sv[256];
    int gid = blockIdx.x * 256 + threadIdx.x;
    int i = idxb[gid];
    preds_out[gid] = (float)rowarg[i];
    sv[threadIdx.x] = rowmax[i];
    __syncthreads();
    for (int s = 128; s > 0; s >>= 1) {
        if (threadIdx.x < s) sv[threadIdx.x] += sv[threadIdx.x + s];
        __syncthreads();
    }
    if (threadIdx.x == 0) partial[blockIdx.x] = sv[0];
}

// ---------- K6: gather rows of src by idx and write transposed (coalesced) ----------
__global__ __launch_bounds__(256) void k_gather(const float* __restrict__ src, int ncols,
                                                const int* __restrict__ idx,
                                                float* __restrict__ dst) {
    __shared__ float rows[64][65];
    int tile = blockIdx.x;
    int col0 = blockIdx.y * 64;
    int tid = threadIdx.x;
    int lane = tid & 63, w = tid >> 6;
    int b = tile >> 6, hw0 = (tile & 63) << 6;
    #pragma unroll
    for (int r8 = 0; r8 < 16; ++r8) {
        int r = w * 16 + r8;
        int row = idx[tile * 64 + r];
        rows[r][lane] = src[(size_t)row * ncols + col0 + lane];
    }
    __syncthreads();
    #pragma unroll
    for (int jj = 0; jj < 16; ++jj) {
        int j = col0 + w * 16 + jj;
        dst[((size_t)b * ncols + j) * HW + hw0 + lane] = rows[lane][w * 16 + jj];
    }
}

// ---------- K7: finalize loss ----------
__global__ __launch_bounds__(128) void k_loss(const float* __restrict__ partial,
                                              float* __restrict__ out) {
    __shared__ float sv[128];
    sv[threadIdx.x] = partial[threadIdx.x];
    __syncthreads();
    for (int s = 64; s > 0; s >>= 1) {
        if (threadIdx.x < s) sv[threadIdx.x] += sv[threadIdx.x + s];
        __syncthreads();
    }
    if (threadIdx.x == 0) out[0] = -(sv[0] / 32768.0f);
}

extern "C" void kernel_launch(void* const* d_in, const int* in_sizes, int n_in,
                              void* d_out, int out_size, void* d_ws, size_t ws_size,
                              hipStream_t stream) {
    const float* x        = (const float*)d_in[0];
    const float* centers  = (const float*)d_in[1];
    const float* clusters = (const float*)d_in[2];
    const float* gumbel   = (const float*)d_in[3];
    float* out = (float*)d_out;

    char* w = (char*)d_ws;
    int*   idxb    = (int*)w;                                  // 128 KB
    float* cnorm   = (float*)(w + 131072);                     // 4 KB
    float* clnorm  = cnorm + 1024;
    float* rowmax  = clnorm + 1024;
    int*   rowarg  = (int*)(rowmax + 1024);
    float* partial = (float*)(rowarg + 1024);
    float* M       = (float*)(w + 262144);                     // 4 MB
    unsigned short* cenB = (unsigned short*)(w + 4456448);     // 1 MB

    float* out_loss  = out;
    float* out_preds = out + 1;
    float* out_ip    = out + 1 + 32768;
    float* out_zq    = out + 1 + 32768 + (size_t)N * NPIX;

    k_norms  <<<2048, 64, 0, stream>>>(centers, clusters, cnorm, clnorm);
    k_gemmM  <<<dim3(16, 16), 256, 0, stream>>>(centers, clusters, cnorm, clnorm, M);
    k_rowstat<<<1024, 256, 0, stream>>>(M, rowmax, rowarg);
    k_cenfrag<<<1024, 64, 0, stream>>>(centers, cenB);
    k_fused  <<<2048, 256, 0, stream>>>(x, cenB, gumbel, centers, idxb);
    k_preds  <<<128, 256, 0, stream>>>(idxb, rowmax, rowarg, out_preds, partial);
    k_gather <<<dim3(512, 16), 256, 0, stream>>>(M, N, idxb, out_ip);
    k_gather <<<dim3(512, 8),  256, 0, stream>>>(centers, C, idxb, out_zq);
    k_loss   <<<1, 128, 0, stream>>>(partial, out_loss);
}

// Round 5
// 247.340 us; speedup vs baseline: 1.1651x; 1.1651x over previous
//
#include <hip/hip_runtime.h>
#include <math.h>

#define C 512
#define HW 4096
#define N 1024
#define NPIX 32768
#define MARGIN 2.0f
#define BLKPX 64
#define WAVES 4

typedef short s16x8 __attribute__((ext_vector_type(8)));
typedef float f32x4 __attribute__((ext_vector_type(4)));

__device__ inline unsigned short f2bf(float f) {
    unsigned int u = __float_as_uint(f);
    return (unsigned short)((u + 0x7FFFu + ((u >> 16) & 1u)) >> 16);
}
__device__ inline float h2f(unsigned short u) {
    _Float16 h; __builtin_memcpy(&h, &u, 2); return (float)h;
}
__device__ inline unsigned short f2h(float f) {
    _Float16 h = (_Float16)f; unsigned short u; __builtin_memcpy(&u, &h, 2); return u;
}
__device__ inline unsigned int mono(float v) {
    unsigned int u = __float_as_uint(v);
    return (u & 0x80000000u) ? ~u : (u | 0x80000000u);
}
// xs layout: [px][k] fp32, 16B granules XOR-swizzled so staging writes,
// fragment reads and refine reads are all (near-)conflict-free.
__device__ inline int xsw(int p, int G) {
    return p * 512 + ((G ^ (((p >> 2) & 7) ^ ((p & 3) << 1))) << 2);
}

// ---------- K0: row norms of centers (->cnorm) and clusters (->clnorm) ----------
__global__ __launch_bounds__(64) void k_norms(const float* __restrict__ centers,
                                              const float* __restrict__ clusters,
                                              float* __restrict__ cnorm,
                                              float* __restrict__ clnorm) {
    int r = blockIdx.x;
    const float* src = (r < N) ? (centers + (size_t)r * C) : (clusters + (size_t)(r - N) * C);
    int lane = threadIdx.x;
    float s = 0.f;
    for (int k = lane; k < C; k += 64) { float v = src[k]; s += v * v; }
    #pragma unroll
    for (int m = 1; m < 64; m <<= 1) s += __shfl_xor(s, m, 64);
    if (lane == 0) {
        float nrm = sqrtf(s);
        if (nrm < 1e-12f) nrm = 1e-12f;
        if (r < N) cnorm[r] = nrm; else clnorm[r - N] = nrm;
    }
}

// ---------- K1: M[i][j] = dot(centers[i],clusters[j]) / (cnorm[i]*clnorm[j]) ----------
__global__ __launch_bounds__(256) void k_gemmM(const float* __restrict__ centers,
                                               const float* __restrict__ clusters,
                                               const float* __restrict__ cnorm,
                                               const float* __restrict__ clnorm,
                                               float* __restrict__ M) {
    __shared__ float as[32][68];
    __shared__ float bs[32][68];
    int tid = threadIdx.x;
    int tx = tid & 15, ty = tid >> 4;
    int i0 = blockIdx.x * 64, j0 = blockIdx.y * 64;
    int lrow = tid >> 2, lkq = (tid & 3) * 8;
    float acc[4][4] = {};
    for (int kc = 0; kc < C; kc += 32) {
        float4 a0 = *(const float4*)(centers + (size_t)(i0 + lrow) * C + kc + lkq);
        float4 a1 = *(const float4*)(centers + (size_t)(i0 + lrow) * C + kc + lkq + 4);
        float4 b0 = *(const float4*)(clusters + (size_t)(j0 + lrow) * C + kc + lkq);
        float4 b1 = *(const float4*)(clusters + (size_t)(j0 + lrow) * C + kc + lkq + 4);
        __syncthreads();
        as[lkq+0][lrow]=a0.x; as[lkq+1][lrow]=a0.y; as[lkq+2][lrow]=a0.z; as[lkq+3][lrow]=a0.w;
        as[lkq+4][lrow]=a1.x; as[lkq+5][lrow]=a1.y; as[lkq+6][lrow]=a1.z; as[lkq+7][lrow]=a1.w;
        bs[lkq+0][lrow]=b0.x; bs[lkq+1][lrow]=b0.y; bs[lkq+2][lrow]=b0.z; bs[lkq+3][lrow]=b0.w;
        bs[lkq+4][lrow]=b1.x; bs[lkq+5][lrow]=b1.y; bs[lkq+6][lrow]=b1.z; bs[lkq+7][lrow]=b1.w;
        __syncthreads();
        #pragma unroll
        for (int k = 0; k < 32; k += 4) {
            float av[4][4], bv[4][4];
            #pragma unroll
            for (int kk = 0; kk < 4; ++kk) {
                float4 ta = *(const float4*)&as[k+kk][tx*4];
                float4 tb = *(const float4*)&bs[k+kk][ty*4];
                av[kk][0]=ta.x; av[kk][1]=ta.y; av[kk][2]=ta.z; av[kk][3]=ta.w;
                bv[kk][0]=tb.x; bv[kk][1]=tb.y; bv[kk][2]=tb.z; bv[kk][3]=tb.w;
            }
            #pragma unroll
            for (int kk = 0; kk < 4; ++kk)
                #pragma unroll
                for (int ii = 0; ii < 4; ++ii)
                    #pragma unroll
                    for (int jj = 0; jj < 4; ++jj)
                        acc[ii][jj] = fmaf(av[kk][ii], bv[kk][jj], acc[ii][jj]);
        }
    }
    float rci[4], rcj[4];
    #pragma unroll
    for (int ii = 0; ii < 4; ++ii) rci[ii] = cnorm[i0 + tx*4 + ii];
    #pragma unroll
    for (int jj = 0; jj < 4; ++jj) rcj[jj] = clnorm[j0 + ty*4 + jj];
    #pragma unroll
    for (int ii = 0; ii < 4; ++ii)
        #pragma unroll
        for (int jj = 0; jj < 4; ++jj)
            M[(size_t)(i0 + tx*4 + ii) * N + (j0 + ty*4 + jj)] = acc[ii][jj] / (rci[ii] * rcj[jj]);
}

// ---------- K2: per-row max + argmax (first-index tie-break) of M ----------
__global__ __launch_bounds__(256) void k_rowstat(const float* __restrict__ M,
                                                 float* __restrict__ rowmax,
                                                 int* __restrict__ rowarg) {
    __shared__ float sv[256];
    __shared__ int   sa[256];
    int i = blockIdx.x, tid = threadIdx.x;
    float bv = -INFINITY; int ba = 0;
    for (int j = tid; j < N; j += 256) {
        float v = M[(size_t)i * N + j];
        if (v > bv || (v == bv && j < ba)) { bv = v; ba = j; }
    }
    sv[tid] = bv; sa[tid] = ba;
    __syncthreads();
    for (int s = 128; s > 0; s >>= 1) {
        if (tid < s) {
            float v = sv[tid + s]; int a = sa[tid + s];
            if (v > sv[tid] || (v == sv[tid] && a < sa[tid])) { sv[tid] = v; sa[tid] = a; }
        }
        __syncthreads();
    }
    if (tid == 0) { rowmax[i] = sv[0]; rowarg[i] = sa[0]; }
}

// ---------- K3: centers -> bf16 MFMA B-fragments (fragment-linear) ----------
__global__ __launch_bounds__(64) void k_cenfrag(const float* __restrict__ centers,
                                                unsigned short* __restrict__ cenB) {
    int f = blockIdx.x;                 // nt*16 + kt
    int nt = f >> 4, kt = f & 15;
    int lane = threadIdx.x;
    int r = lane & 15, g = lane >> 4;
    const float* src = centers + (size_t)(nt * 16 + r) * C + kt * 32 + g * 4;
    float4 lo = *(const float4*)src;
    float4 hi = *(const float4*)(src + 16);
    union { unsigned short us[8]; uint4 q; } u;
    u.us[0]=f2bf(lo.x); u.us[1]=f2bf(lo.y); u.us[2]=f2bf(lo.z); u.us[3]=f2bf(lo.w);
    u.us[4]=f2bf(hi.x); u.us[5]=f2bf(hi.y); u.us[6]=f2bf(hi.z); u.us[7]=f2bf(hi.w);
    *(uint4*)(cenB + ((size_t)f * 64 + lane) * 8) = u.q;
}

// ---------- K4: FUSED — 64px/block, LDS-broadcast codebook tiles, on-the-fly candidates ----------
__global__ __launch_bounds__(256, 1) void k_fused(const float* __restrict__ x,
                                                  const unsigned short* __restrict__ cenB,
                                                  const float* __restrict__ gumbel,
                                                  const float* __restrict__ centers,
                                                  int* __restrict__ idxb) {
    __shared__ float xs[BLKPX * 512];                // 128 KB fp32 tile of x (swizzled)
    __shared__ unsigned short cen[16 * 512];         // 16 KB: one 16n x 512k bf16 tile
    __shared__ unsigned long long pixkey[BLKPX];     // 512 B
    __shared__ unsigned int candlist[WAVES][256];    // 4 KB
    __shared__ int candcount[WAVES];

    int tid = threadIdx.x;
    int lane = tid & 63, w = tid >> 6;
    int r = lane & 15, g = lane >> 4;

    int p0 = blockIdx.x * BLKPX;
    int b = p0 >> 12, hw0 = p0 & (HW - 1);

    if (tid < BLKPX) pixkey[tid] = 0ull;
    if (tid < WAVES) candcount[tid] = 0;

    // ---- stage cen tile 0 (16 KB straight copy, conflict-free) ----
    const uint4* cb = (const uint4*)cenB;            // tile nt at cb + nt*1024
    uint4* cl = (uint4*)cen;
    #pragma unroll
    for (int j = 0; j < 4; ++j) cl[j * 256 + tid] = cb[j * 256 + tid];

    // ---- stage x tile: 512 k x 64 px fp32, coalesced reads, swizzled scalar writes ----
    const float* xb = x + (size_t)b * C * HW + hw0;
    {
        int q = tid & 15, k0 = tid >> 4;
        #pragma unroll
        for (int kk = 0; kk < 32; ++kk) {
            int k = kk * 16 + k0;
            float4 v = *(const float4*)(xb + (size_t)k * HW + q * 4);
            int G = k >> 2, e = k & 3;
            xs[xsw(q * 4 + 0, G) + e] = v.x;
            xs[xsw(q * 4 + 1, G) + e] = v.y;
            xs[xsw(q * 4 + 2, G) + e] = v.z;
            xs[xsw(q * 4 + 3, G) + e] = v.w;
        }
    }
    __syncthreads();

    // ---- prefetch cen tile 1 to regs; prefetch gumbel nt=0,1 ----
    uint4 cr0 = cb[1024 + tid], cr1 = cb[1280 + tid], cr2 = cb[1536 + tid], cr3 = cb[1792 + tid];
    const float* gbase = gumbel + (size_t)b * N * HW + hw0 + w * 16 + g * 4;
    float4 gv_c = *(const float4*)(gbase + (size_t)r * HW);
    float4 gv_n = *(const float4*)(gbase + (size_t)(16 + r) * HW);

    // ---- A fragments: wave w's 16 px x 512 k bf16, from swizzled LDS ----
    s16x8 a[16];
    #pragma unroll
    for (int kt = 0; kt < 16; ++kt) {
        float4 lo = *(const float4*)&xs[xsw(w * 16 + r, kt * 8 + g)];
        float4 hi = *(const float4*)&xs[xsw(w * 16 + r, kt * 8 + 4 + g)];
        s16x8 t;
        t[0] = (short)f2bf(lo.x); t[1] = (short)f2bf(lo.y);
        t[2] = (short)f2bf(lo.z); t[3] = (short)f2bf(lo.w);
        t[4] = (short)f2bf(hi.x); t[5] = (short)f2bf(hi.y);
        t[6] = (short)f2bf(hi.z); t[7] = (short)f2bf(hi.w);
        a[kt] = t;
    }

    // ---- main sweep: 64 n-tiles, all waves in lockstep on the LDS tile ----
    float m4[4] = {-INFINITY, -INFINITY, -INFINITY, -INFINITY};
    for (int ntc = 0; ntc < 8; ++ntc) {
        unsigned int keepH[16];
        #pragma unroll
        for (int s = 0; s < 8; ++s) {
            int nt = ntc * 8 + s;
            int ntf = (nt + 2 <= 63) ? nt + 2 : 63;
            float4 gv_f = *(const float4*)(gbase + (size_t)(ntf * 16 + r) * HW);
            // MFMA phase on LDS tile (currently holds tile nt)
            const s16x8* bp = (const s16x8*)cen + lane;
            f32x4 acc0 = {0.f, 0.f, 0.f, 0.f};
            f32x4 acc1 = {0.f, 0.f, 0.f, 0.f};
            #pragma unroll
            for (int kt = 0; kt < 16; kt += 2) {
                s16x8 b0 = bp[kt * 64];
                s16x8 b1 = bp[(kt + 1) * 64];
                acc0 = __builtin_amdgcn_mfma_f32_16x16x32_bf16(a[kt],     b0, acc0, 0, 0, 0);
                acc1 = __builtin_amdgcn_mfma_f32_16x16x32_bf16(a[kt + 1], b1, acc1, 0, 0, 0);
            }
            float v0 = acc0[0] + acc1[0] + gv_c.x;
            float v1 = acc0[1] + acc1[1] + gv_c.y;
            float v2 = acc0[2] + acc1[2] + gv_c.z;
            float v3 = acc0[3] + acc1[3] + gv_c.w;
            m4[0] = fmaxf(m4[0], v0); m4[1] = fmaxf(m4[1], v1);
            m4[2] = fmaxf(m4[2], v2); m4[3] = fmaxf(m4[3], v3);
            keepH[s * 2]     = (unsigned int)f2h(v0) | ((unsigned int)f2h(v1) << 16);
            keepH[s * 2 + 1] = (unsigned int)f2h(v2) | ((unsigned int)f2h(v3) << 16);
            __builtin_amdgcn_s_barrier();            // everyone done reading tile nt
            __builtin_amdgcn_sched_barrier(0);
            // write tile nt+1 (compiler inserts counted vmcnt for cr*)
            cl[tid] = cr0; cl[256 + tid] = cr1; cl[512 + tid] = cr2; cl[768 + tid] = cr3;
            {
                const uint4* src = cb + (size_t)ntf * 1024;   // prefetch tile nt+2
                cr0 = src[tid]; cr1 = src[256 + tid]; cr2 = src[512 + tid]; cr3 = src[768 + tid];
            }
            asm volatile("s_waitcnt lgkmcnt(0)" ::: "memory");
            __builtin_amdgcn_s_barrier();            // tile nt+1 visible
            __builtin_amdgcn_sched_barrier(0);
            gv_c = gv_n; gv_n = gv_f;
        }
        // ---- chunk scan: per-pixel max across r-lanes, then candidate pushes ----
        #pragma unroll
        for (int s2 = 1; s2 < 16; s2 <<= 1) {
            #pragma unroll
            for (int j = 0; j < 4; ++j) m4[j] = fmaxf(m4[j], __shfl_xor(m4[j], s2, 64));
        }
        float thr[4];
        #pragma unroll
        for (int j = 0; j < 4; ++j) thr[j] = m4[j] - MARGIN;
        #pragma unroll
        for (int s = 0; s < 8; ++s) {
            int nn = (ntc * 8 + s) * 16 + r;
            #pragma unroll
            for (int j2 = 0; j2 < 2; ++j2) {
                unsigned int pk = keepH[s * 2 + j2];
                float lo = h2f((unsigned short)(pk & 0xFFFFu));
                float hi = h2f((unsigned short)(pk >> 16));
                if (lo >= thr[j2 * 2]) {
                    int pos = atomicAdd(&candcount[w], 1);
                    if (pos < 256) candlist[w][pos] =
                        (unsigned int)nn | ((unsigned int)(w * 16 + g * 4 + j2 * 2) << 10);
                }
                if (hi >= thr[j2 * 2 + 1]) {
                    int pos = atomicAdd(&candcount[w], 1);
                    if (pos < 256) candlist[w][pos] =
                        (unsigned int)nn | ((unsigned int)(w * 16 + g * 4 + j2 * 2 + 1) << 10);
                }
            }
        }
    }

    // ---- exact fp32 refine: 4 candidates per wave in parallel (16-lane groups) ----
    int cc = candcount[w]; if (cc > 256) cc = 256;
    int sl = lane & 15, cg = lane >> 4;
    for (int t0 = 0; t0 < cc; t0 += 4) {
        int c = t0 + cg;
        bool valid = c < cc;
        unsigned int e = candlist[w][valid ? c : 0];
        int n = (int)(e & 1023u), pl = (int)(e >> 10);
        const float* cenr = centers + (size_t)n * C;
        float s = 0.f;
        #pragma unroll
        for (int m = 0; m < 8; ++m) {
            int G = sl + (m << 4);
            float4 xv = *(const float4*)&xs[xsw(pl, G)];
            float4 cv = *(const float4*)(cenr + (G << 2));
            s = fmaf(xv.x, cv.x, s); s = fmaf(xv.y, cv.y, s);
            s = fmaf(xv.z, cv.z, s); s = fmaf(xv.w, cv.w, s);
        }
        #pragma unroll
        for (int s2 = 1; s2 < 16; s2 <<= 1) s += __shfl_xor(s, s2, 64);
        if (valid && sl == 0) {
            float val = s + gumbel[((size_t)b * N + n) * HW + hw0 + pl];
            unsigned long long key = ((unsigned long long)mono(val) << 32) | (unsigned int)(1023 - n);
            atomicMax(&pixkey[pl], key);
        }
    }
    __syncthreads();
    if (tid < BLKPX) idxb[p0 + tid] = 1023 - (int)(unsigned int)(pixkey[tid] & 0xFFFFFFFFull);
}

// ---------- K5: preds (as float) + per-block loss partial sums ----------
__global__ __launch_bounds__(256) void k_preds(const int* __restrict__ idxb,
                                               const float* __restrict__ rowmax,
                                               const int* __restrict__ rowarg,
                                               float* __restrict__ preds_out,
                                               float* __restrict__ partial) {
    __shared__ float sv[256];
    int gid = blockIdx.x * 256 + threadIdx.x;
    int i = idxb[gid];
    preds_out[gid] = (float)rowarg[i];
    sv[threadIdx.x] = rowmax[i];
    __syncthreads();
    for (int s = 128; s > 0; s >>= 1) {
        if (threadIdx.x < s) sv[threadIdx.x] += sv[threadIdx.x + s];
        __syncthreads();
    }
    if (threadIdx.x == 0) partial[blockIdx.x] = sv[0];
}

// ---------- K6: gather rows of src by idx and write transposed (coalesced) ----------
__global__ __launch_bounds__(256) void k_gather(const float* __restrict__ src, int ncols,
                                                const int* __restrict__ idx,
                                                float* __restrict__ dst) {
    __shared__ float rows[64][65];
    int tile = blockIdx.x;
    int col0 = blockIdx.y * 64;
    int tid = threadIdx.x;
    int lane = tid & 63, w = tid >> 6;
    int b = tile >> 6, hw0 = (tile & 63) << 6;
    #pragma unroll
    for (int r8 = 0; r8 < 16; ++r8) {
        int r = w * 16 + r8;
        int row = idx[tile * 64 + r];
        rows[r][lane] = src[(size_t)row * ncols + col0 + lane];
    }
    __syncthreads();
    #pragma unroll
    for (int jj = 0; jj < 16; ++jj) {
        int j = col0 + w * 16 + jj;
        dst[((size_t)b * ncols + j) * HW + hw0 + lane] = rows[lane][w * 16 + jj];
    }
}

// ---------- K7: finalize loss ----------
__global__ __launch_bounds__(128) void k_loss(const float* __restrict__ partial,
                                              float* __restrict__ out) {
    __shared__ float sv[128];
    sv[threadIdx.x] = partial[threadIdx.x];
    __syncthreads();
    for (int s = 64; s > 0; s >>= 1) {
        if (threadIdx.x < s) sv[threadIdx.x] += sv[threadIdx.x + s];
        __syncthreads();
    }
    if (threadIdx.x == 0) out[0] = -(sv[0] / 32768.0f);
}

extern "C" void kernel_launch(void* const* d_in, const int* in_sizes, int n_in,
                              void* d_out, int out_size, void* d_ws, size_t ws_size,
                              hipStream_t stream) {
    const float* x        = (const float*)d_in[0];
    const float* centers  = (const float*)d_in[1];
    const float* clusters = (const float*)d_in[2];
    const float* gumbel   = (const float*)d_in[3];
    float* out = (float*)d_out;

    char* w = (char*)d_ws;
    int*   idxb    = (int*)w;                                  // 128 KB
    float* cnorm   = (float*)(w + 131072);                     // 4 KB
    float* clnorm  = cnorm + 1024;
    float* rowmax  = clnorm + 1024;
    int*   rowarg  = (int*)(rowmax + 1024);
    float* partial = (float*)(rowarg + 1024);
    float* M       = (float*)(w + 262144);                     // 4 MB
    unsigned short* cenB = (unsigned short*)(w + 4456448);     // 1 MB

    float* out_loss  = out;
    float* out_preds = out + 1;
    float* out_ip    = out + 1 + 32768;
    float* out_zq    = out + 1 + 32768 + (size_t)N * NPIX;

    k_norms  <<<2048, 64, 0, stream>>>(centers, clusters, cnorm, clnorm);
    k_gemmM  <<<dim3(16, 16), 256, 0, stream>>>(centers, clusters, cnorm, clnorm, M);
    k_rowstat<<<1024, 256, 0, stream>>>(M, rowmax, rowarg);
    k_cenfrag<<<1024, 64, 0, stream>>>(centers, cenB);
    k_fused  <<<512, 256, 0, stream>>>(x, cenB, gumbel, centers, idxb);
    k_preds  <<<128, 256, 0, stream>>>(idxb, rowmax, rowarg, out_preds, partial);
    k_gather <<<dim3(512, 16), 256, 0, stream>>>(M, N, idxb, out_ip);
    k_gather <<<dim3(512, 8),  256, 0, stream>>>(centers, C, idxb, out_zq);
    k_loss   <<<1, 128, 0, stream>>>(partial, out_loss);
}